// Round 3
// baseline (190.286 us; speedup 1.0000x reference)
//
#include <hip/hip_runtime.h>
#include <cstdint>
#include <cstddef>

#define N_IMG 32
#define C_IN 192
#define HW 56
#define SPAT 3136
#define C_OUT 384
#define HP 58
#define KPOS 9
#define KTOT 1728          // 9*192
#define NT 27              // K-tiles of 64

#define BM 128             // Cout per block
#define BN 256             // spatial-flat per block
#define NT_CO 3
#define NT_S  392          // 100352/256 exact
#define GRID_MAIN (NT_CO*NT_S)   // 1176, %8 == 0

#define BUF_EL 24576       // (128+256)*64 bf16 elements per buffer (48KB)
#define B_BASE 8192        // B region starts after A[128][64]

typedef __attribute__((ext_vector_type(8))) short short8;
typedef __attribute__((ext_vector_type(4))) float f32x4;

__device__ __forceinline__ unsigned short f2bf(float f) {
  union { float f; unsigned u; } v; v.f = f;
  unsigned u = v.u;
  unsigned r = (u + 0x7FFFu + ((u >> 16) & 1u)) >> 16;
  return (unsigned short)r;
}

__device__ __forceinline__ void async_load16(const void* gsrc, void* ldst) {
  __builtin_amdgcn_global_load_lds(
      (const __attribute__((address_space(1))) unsigned int*)gsrc,
      (__attribute__((address_space(3))) unsigned int*)ldst,
      16, 0, 0);
}

__device__ __forceinline__ void vm6() { asm volatile("s_waitcnt vmcnt(6)" ::: "memory"); }
__device__ __forceinline__ void vm0() { asm volatile("s_waitcnt vmcnt(0)" ::: "memory"); }

// ---- prep: W (Cout,C,3,3) f32 -> Wp[co][pos][c] bf16 (K linear = pos*192+c) ----
__global__ void pack_w(const float* __restrict__ W, unsigned short* __restrict__ Wp) {
  int idx = blockIdx.x*256 + threadIdx.x;
  if (idx >= C_OUT*KPOS*C_IN) return;
  int c   = idx % C_IN;
  int pos = (idx / C_IN) % KPOS;
  int co  = idx / (C_IN*KPOS);
  float v = W[((size_t)co*C_IN + c)*KPOS + pos];
  Wp[idx] = f2bf(v);
}

// ---- prep: zero pad border of Xp[n][58][58][192] ----
__global__ void zero_border(unsigned short* __restrict__ Xp) {
  int idx = blockIdx.x*256 + threadIdx.x;
  if (idx >= N_IMG*228*C_IN) return;
  int c    = idx % C_IN;
  int cell = (idx / C_IN) % 228;
  int n    = idx / (C_IN*228);
  int hh, ww;
  if (cell < 116) { hh = (cell < 58) ? 0 : 57; ww = cell % 58; }
  else { int b2 = cell - 116; ww = (b2 < 56) ? 0 : 57; hh = 1 + (b2 % 56); }
  Xp[(((size_t)n*HP + hh)*HP + ww)*C_IN + c] = 0;
}

// ---- prep: x NCHW f32 -> Xp padded NHWC bf16 (interior) ----
__global__ void pack_x(const float* __restrict__ x, unsigned short* __restrict__ Xp) {
  __shared__ float tile[64*57];
  int b  = blockIdx.x;
  int cb = b % 3;
  int h  = (b/3) % HW;
  int n  = b / (3*HW);
  int tid = threadIdx.x;
  const float* src = x + (size_t)n*C_IN*SPAT + (size_t)cb*64*SPAT + h*HW;
  #pragma unroll
  for (int i = 0; i < 14; ++i) {
    int idx = i*256 + tid;
    int c = idx / HW, w = idx % HW;
    tile[c*57 + w] = src[(size_t)c*SPAT + w];
  }
  __syncthreads();
  unsigned short* dst = Xp + (((size_t)n*HP + h + 1)*HP + 1)*C_IN + cb*64;
  #pragma unroll
  for (int i = 0; i < 14; ++i) {
    int idx = i*256 + tid;
    int w = idx / 64, c = idx % 64;
    dst[(size_t)w*C_IN + c] = f2bf(tile[c*57 + w]);
  }
}

// ---- main: implicit-GEMM conv, 128x256 tile, 8 waves, ring-3 K=64, counted vmcnt ----
__global__ __launch_bounds__(512, 2) void conv_gemm(
    const unsigned short* __restrict__ Wp,
    const unsigned short* __restrict__ Xp,
    const float* __restrict__ bias,
    float* __restrict__ out)
{
  __shared__ __attribute__((aligned(16))) unsigned short lds[3][BUF_EL];  // 144 KB

  int bid = blockIdx.x;
  int wg = (bid & 7) * (GRID_MAIN/8) + (bid >> 3);   // XCD-bijective (1176%8==0)
  int cotile = wg % NT_CO;
  int stile  = wg / NT_CO;

  const int tid   = threadIdx.x;
  const int lane  = tid & 63;
  const int wv    = tid >> 6;       // 0..7
  const int wm    = wv >> 2;        // 0..1  (M / Cout position)
  const int wn    = wv & 3;         // 0..3  (N / spatial position)
  const int lanep = lane & 15;
  const int laneq = lane >> 4;
  const int l3    = lane >> 3;      // staging row within 8-row chunk
  const int l7    = lane & 7;       // staging 16B slot within 128B row
  const int gsl   = (l7 ^ l3) << 3; // pre-swizzled source chunk offset (elements)

  // ---- staging source pointers ----
  // A: 16 chunks of 8 rows; wave wv handles chunks wv and wv+8
  const unsigned short* aSrc0;
  const unsigned short* aSrc1;
  {
    int r0 = (0*8 + wv)*8 + l3;
    aSrc0 = Wp + (size_t)(cotile*BM + r0)*KTOT + gsl;
    int r1 = (1*8 + wv)*8 + l3;
    aSrc1 = Wp + (size_t)(cotile*BM + r1)*KTOT + gsl;
  }
  const int aOff0 = (0*8 + wv)*512;   // LDS element offsets (chunk*512)
  const int aOff1 = (1*8 + wv)*512;

  // B: 32 chunks of 8 rows; wave wv handles chunks i*8+wv, i=0..3
  const unsigned short* bSrc[4];
  int bOff[4];
  #pragma unroll
  for (int i = 0; i < 4; ++i) {
    int cbk = i*8 + wv;
    int rb  = cbk*8 + l3;
    int f   = stile*BN + rb;
    int n   = f / SPAT, sp = f % SPAT;
    bSrc[i] = Xp + (((size_t)n*HP + sp/HW)*HP + sp%HW)*C_IN + gsl;
    bOff[i] = B_BASE + cbk*512;
  }

  // ds_read fragment bases (elements; frag mf/nf adds mf*1024; kk flips XOR 32)
  const int swz = (laneq ^ l7) << 3;      // l7 == lanep&7 for the read lanes
  const int aRd = (wm*64 + lanep)*64 + ((laneq ^ (lanep & 7)) << 3);
  const int bRd = B_BASE + (wn*64 + lanep)*64 + ((laneq ^ (lanep & 7)) << 3);
  (void)swz;

  f32x4 acc[4][4];
  #pragma unroll
  for (int mf = 0; mf < 4; ++mf)
    #pragma unroll
    for (int nf = 0; nf < 4; ++nf)
      acc[mf][nf] = (f32x4){0.f, 0.f, 0.f, 0.f};

  // K-tile t -> B image offset (all 64 K of a tile sit in one conv position)
  auto bOffOf = [](int t) {
    int pos = t / 3;                 // 0..8
    int c0  = (t - pos*3) * 64;      // 0,64,128
    int kh  = pos / 3, kw = pos - kh*3;
    return (kh*HP + kw)*C_IN + c0;
  };

  auto stage = [&](int t, unsigned short* base) {
    const int koff = t*64;
    async_load16(aSrc0 + koff, base + aOff0);
    async_load16(aSrc1 + koff, base + aOff1);
    const int bo = bOffOf(t);
    #pragma unroll
    for (int i = 0; i < 4; ++i)
      async_load16(bSrc[i] + bo, base + bOff[i]);
  };

#define PHASE(LB, KK, STAGE_STMT, VM_STMT)                                  \
  {                                                                         \
    const unsigned short* lb_ = (LB);                                       \
    short8 av_[4], bv_[4];                                                  \
    _Pragma("unroll")                                                       \
    for (int mf = 0; mf < 4; ++mf)                                          \
      av_[mf] = *(const short8*)&lb_[(aRd + mf*1024) ^ ((KK)*32)];          \
    _Pragma("unroll")                                                       \
    for (int nf = 0; nf < 4; ++nf)                                          \
      bv_[nf] = *(const short8*)&lb_[(bRd + nf*1024) ^ ((KK)*32)];          \
    STAGE_STMT;                                                             \
    __builtin_amdgcn_sched_barrier(0);                                      \
    __builtin_amdgcn_s_barrier();                                           \
    asm volatile("s_waitcnt lgkmcnt(0)" ::: "memory");                      \
    __builtin_amdgcn_sched_barrier(0);                                      \
    __builtin_amdgcn_s_setprio(1);                                          \
    _Pragma("unroll")                                                       \
    for (int mf = 0; mf < 4; ++mf)                                          \
      _Pragma("unroll")                                                     \
      for (int nf = 0; nf < 4; ++nf)                                        \
        acc[mf][nf] = __builtin_amdgcn_mfma_f32_16x16x32_bf16(              \
            av_[mf], bv_[nf], acc[mf][nf], 0, 0, 0);                        \
    __builtin_amdgcn_s_setprio(0);                                          \
    __builtin_amdgcn_sched_barrier(0);                                      \
    VM_STMT;                                                                \
    __builtin_amdgcn_s_barrier();                                           \
  }

  unsigned short* b0 = &lds[0][0];
  unsigned short* b1 = &lds[1][0];
  unsigned short* b2 = &lds[2][0];

  // prologue: stage tiles 0,1 (12 loads/wave); wait stage(0) landed
  stage(0, b0);
  stage(1, b1);
  vm6();
  __builtin_amdgcn_s_barrier();

  for (int t0 = 0; t0 < NT; t0 += 3) {
    // tile t0 (buffer 0); stage t0+2 -> buffer 2
    PHASE(b0, 0, { if (t0 + 2 < NT) stage(t0 + 2, b2); }, );
    PHASE(b0, 1, , { if (t0     < NT-2) vm6(); else vm0(); });
    // tile t0+1 (buffer 1); stage t0+3 -> buffer 0
    PHASE(b1, 0, { if (t0 + 3 < NT) stage(t0 + 3, b0); }, );
    PHASE(b1, 1, , { if (t0 + 1 < NT-2) vm6(); else vm0(); });
    // tile t0+2 (buffer 2); stage t0+4 -> buffer 1
    PHASE(b2, 0, { if (t0 + 4 < NT) stage(t0 + 4, b1); }, );
    PHASE(b2, 1, , { if (t0 + 2 < NT-2) vm6(); else vm0(); });
  }
#undef PHASE

  // ---- epilogue: D col = lane&15 -> spatial, row = laneq*4+i -> Cout ----
  const int coB = cotile*BM + wm*64;
  const int fB  = stile*BN + wn*64;
  #pragma unroll
  for (int nf = 0; nf < 4; ++nf) {
    int f  = fB + nf*16 + lanep;
    int n  = f / SPAT;
    int sp = f % SPAT;
    float* obase = out + (size_t)n*C_OUT*SPAT + sp;
    #pragma unroll
    for (int mf = 0; mf < 4; ++mf) {
      #pragma unroll
      for (int i = 0; i < 4; ++i) {
        int co = coB + mf*16 + laneq*4 + i;
        obase[(size_t)co*SPAT] = acc[mf][nf][i] + bias[co];
      }
    }
  }
}

// ---- fallback: direct fp32 conv (used only if ws too small) ----
__global__ void conv_naive(const float* __restrict__ x, const float* __restrict__ W,
                           const float* __restrict__ bias, float* __restrict__ out) {
  size_t idx = (size_t)blockIdx.x*256 + threadIdx.x;
  if (idx >= (size_t)N_IMG*C_OUT*SPAT) return;
  int s  = idx % SPAT;
  int co = (int)((idx / SPAT) % C_OUT);
  int n  = (int)(idx / ((size_t)SPAT*C_OUT));
  int h = s / HW, w = s % HW;
  float acc = bias[co];
  for (int c = 0; c < C_IN; ++c)
    for (int kh = 0; kh < 3; ++kh) {
      int hh = h + kh - 1;
      if (hh < 0 || hh >= HW) continue;
      for (int kw = 0; kw < 3; ++kw) {
        int ww = w + kw - 1;
        if (ww < 0 || ww >= HW) continue;
        acc += x[(((size_t)n*C_IN + c)*HW + hh)*HW + ww]
             * W[(((size_t)co*C_IN + c)*3 + kh)*3 + kw];
      }
    }
  out[idx] = acc;
}

extern "C" void kernel_launch(void* const* d_in, const int* in_sizes, int n_in,
                              void* d_out, int out_size, void* d_ws, size_t ws_size,
                              hipStream_t stream) {
  const float* x = (const float*)d_in[0];
  const float* W = (const float*)d_in[1];
  const float* b = (const float*)d_in[2];
  float* out = (float*)d_out;

  const size_t WP_ELEMS = (size_t)C_OUT*KPOS*C_IN;        // 663,552
  const size_t XP_ELEMS = (size_t)N_IMG*HP*HP*C_IN;       // 20,668,416
  const size_t NEED = (WP_ELEMS + XP_ELEMS)*2;            // ~40.7 MB

  if (ws_size >= NEED) {
    unsigned short* Wp = (unsigned short*)d_ws;
    unsigned short* Xp = Wp + WP_ELEMS;                   // 16B-aligned
    zero_border<<<(N_IMG*228*C_IN + 255)/256, 256, 0, stream>>>(Xp);
    pack_w<<<(int)((WP_ELEMS + 255)/256), 256, 0, stream>>>(W, Wp);
    pack_x<<<N_IMG*HW*3, 256, 0, stream>>>(x, Xp);
    conv_gemm<<<GRID_MAIN, 512, 0, stream>>>(Wp, Xp, b, out);
  } else {
    size_t total = (size_t)N_IMG*C_OUT*SPAT;
    conv_naive<<<(int)((total + 255)/256), 256, 0, stream>>>(x, W, b, out);
  }
}

// Round 4
// 166.256 us; speedup vs baseline: 1.1445x; 1.1445x over previous
//
#include <hip/hip_runtime.h>
#include <cstdint>
#include <cstddef>

#define N_IMG 32
#define C_IN 192
#define HW 56
#define SPAT 3136
#define C_OUT 384
#define HP 58
#define KPOS 9
#define KTOT 1728          // 9*192
#define NT 27              // K-tiles of 64

#define BM 128             // Cout per block
#define BN 256             // spatial-flat per block
#define NT_CO 3
#define NT_S  392          // 100352/256 exact
#define GRID_MAIN (NT_CO*NT_S)   // 1176, %8 == 0

#define BUF_EL 24576       // (128+256)*64 bf16 elements per buffer (48KB)
#define B_BASE 8192        // B region starts after A[128][64]

typedef __attribute__((ext_vector_type(8))) short short8;
typedef __attribute__((ext_vector_type(4))) float f32x4;

__device__ __forceinline__ unsigned short f2bf(float f) {
  union { float f; unsigned u; } v; v.f = f;
  unsigned u = v.u;
  unsigned r = (u + 0x7FFFu + ((u >> 16) & 1u)) >> 16;
  return (unsigned short)r;
}

__device__ __forceinline__ void async_load16(const void* gsrc, void* ldst) {
  __builtin_amdgcn_global_load_lds(
      (const __attribute__((address_space(1))) unsigned int*)gsrc,
      (__attribute__((address_space(3))) unsigned int*)ldst,
      16, 0, 0);
}

__device__ __forceinline__ void vm6() { asm volatile("s_waitcnt vmcnt(6)" ::: "memory"); }
__device__ __forceinline__ void vm0() { asm volatile("s_waitcnt vmcnt(0)" ::: "memory"); }

// ---- prep: W (Cout,C,3,3) f32 -> Wp[co][pos][c] bf16 (K linear = pos*192+c) ----
__global__ void pack_w(const float* __restrict__ W, unsigned short* __restrict__ Wp) {
  int idx = blockIdx.x*256 + threadIdx.x;
  if (idx >= C_OUT*KPOS*C_IN) return;
  int c   = idx % C_IN;
  int pos = (idx / C_IN) % KPOS;
  int co  = idx / (C_IN*KPOS);
  float v = W[((size_t)co*C_IN + c)*KPOS + pos];
  Wp[idx] = f2bf(v);
}

// ---- prep: zero pad border of Xp[n][58][58][192] ----
__global__ void zero_border(unsigned short* __restrict__ Xp) {
  int idx = blockIdx.x*256 + threadIdx.x;
  if (idx >= N_IMG*228*C_IN) return;
  int c    = idx % C_IN;
  int cell = (idx / C_IN) % 228;
  int n    = idx / (C_IN*228);
  int hh, ww;
  if (cell < 116) { hh = (cell < 58) ? 0 : 57; ww = cell % 58; }
  else { int b2 = cell - 116; ww = (b2 < 56) ? 0 : 57; hh = 1 + (b2 % 56); }
  Xp[(((size_t)n*HP + hh)*HP + ww)*C_IN + c] = 0;
}

// ---- prep: x NCHW f32 -> Xp padded NHWC bf16 (interior) ----
__global__ void pack_x(const float* __restrict__ x, unsigned short* __restrict__ Xp) {
  __shared__ float tile[64*57];
  int b  = blockIdx.x;
  int cb = b % 3;
  int h  = (b/3) % HW;
  int n  = b / (3*HW);
  int tid = threadIdx.x;
  const float* src = x + (size_t)n*C_IN*SPAT + (size_t)cb*64*SPAT + h*HW;
  #pragma unroll
  for (int i = 0; i < 14; ++i) {
    int idx = i*256 + tid;
    int c = idx / HW, w = idx % HW;
    tile[c*57 + w] = src[(size_t)c*SPAT + w];
  }
  __syncthreads();
  unsigned short* dst = Xp + (((size_t)n*HP + h + 1)*HP + 1)*C_IN + cb*64;
  #pragma unroll
  for (int i = 0; i < 14; ++i) {
    int idx = i*256 + tid;
    int w = idx / 64, c = idx % 64;
    dst[(size_t)w*C_IN + c] = f2bf(tile[c*57 + w]);
  }
}

// ---- main: implicit-GEMM conv, 128x256 tile, 8 waves, ring-3 K=64,
//      ONE phase per K-tile, ONE barrier per phase, counted vmcnt ----
__global__ __launch_bounds__(512, 2) void conv_gemm(
    const unsigned short* __restrict__ Wp,
    const unsigned short* __restrict__ Xp,
    const float* __restrict__ bias,
    float* __restrict__ out)
{
  __shared__ __attribute__((aligned(16))) unsigned short lds[3][BUF_EL];  // 144 KB

  int bid = blockIdx.x;
  int wg = (bid & 7) * (GRID_MAIN/8) + (bid >> 3);   // XCD-bijective (1176%8==0)
  int cotile = wg % NT_CO;
  int stile  = wg / NT_CO;

  const int tid   = threadIdx.x;
  const int lane  = tid & 63;
  const int wv    = tid >> 6;       // 0..7
  const int wm    = wv >> 2;        // 0..1  (M / Cout position)
  const int wn    = wv & 3;         // 0..3  (N / spatial position)
  const int lanep = lane & 15;
  const int laneq = lane >> 4;
  const int l3    = lane >> 3;      // staging row within 8-row chunk
  const int l7    = lane & 7;       // staging 16B slot within 128B row
  const int gsl   = (l7 ^ l3) << 3; // pre-swizzled source chunk offset (elements)

  // ---- staging source pointers ----
  // A: 16 chunks of 8 rows; wave wv handles chunks wv and wv+8
  const unsigned short* aSrc0 = Wp + (size_t)(cotile*BM + wv*8      + l3)*KTOT + gsl;
  const unsigned short* aSrc1 = Wp + (size_t)(cotile*BM + (wv+8)*8  + l3)*KTOT + gsl;
  const int aOff0 = wv*512;
  const int aOff1 = (wv+8)*512;

  // B: 32 chunks of 8 rows; wave wv handles chunks i*8+wv, i=0..3
  const unsigned short* bSrc[4];
  int bOff[4];
  #pragma unroll
  for (int i = 0; i < 4; ++i) {
    int cbk = i*8 + wv;
    int rb  = cbk*8 + l3;
    int f   = stile*BN + rb;
    int n   = f / SPAT, sp = f % SPAT;
    bSrc[i] = Xp + (((size_t)n*HP + sp/HW)*HP + sp%HW)*C_IN + gsl;
    bOff[i] = B_BASE + cbk*512;
  }

  // ds_read fragment bases (elements; frag mf/nf adds mf*1024; kk flips XOR 32)
  const int aRd = (wm*64 + lanep)*64 + ((laneq ^ (lanep & 7)) << 3);
  const int bRd = B_BASE + (wn*64 + lanep)*64 + ((laneq ^ (lanep & 7)) << 3);

  f32x4 acc[4][4];
  #pragma unroll
  for (int mf = 0; mf < 4; ++mf)
    #pragma unroll
    for (int nf = 0; nf < 4; ++nf)
      acc[mf][nf] = (f32x4){0.f, 0.f, 0.f, 0.f};

  // K-tile t -> B image offset (all 64 K of a tile sit in one conv position)
  auto bOffOf = [](int t) {
    int pos = t / 3;                 // 0..8
    int c0  = (t - pos*3) * 64;      // 0,64,128
    int kh  = pos / 3, kw = pos - kh*3;
    return (kh*HP + kw)*C_IN + c0;
  };

  auto stage = [&](int t, unsigned short* base) {
    const int koff = t*64;
    async_load16(aSrc0 + koff, base + aOff0);
    async_load16(aSrc1 + koff, base + aOff1);
    const int bo = bOffOf(t);
    #pragma unroll
    for (int i = 0; i < 4; ++i)
      async_load16(bSrc[i] + bo, base + bOff[i]);
  };

  // One phase = one full K=64 tile: 16 ds_read_b128, stage, 32 MFMA, vm, barrier.
#define PHASE(LB, STAGE_STMT, VM_STMT, DO_BAR)                              \
  {                                                                         \
    const unsigned short* lb_ = (LB);                                       \
    short8 a0_[4], b0_[4], a1_[4], b1_[4];                                  \
    _Pragma("unroll")                                                       \
    for (int mf = 0; mf < 4; ++mf) a0_[mf] = *(const short8*)&lb_[aRd + mf*1024];        \
    _Pragma("unroll")                                                       \
    for (int nf = 0; nf < 4; ++nf) b0_[nf] = *(const short8*)&lb_[bRd + nf*1024];        \
    _Pragma("unroll")                                                       \
    for (int mf = 0; mf < 4; ++mf) a1_[mf] = *(const short8*)&lb_[(aRd + mf*1024) ^ 32]; \
    _Pragma("unroll")                                                       \
    for (int nf = 0; nf < 4; ++nf) b1_[nf] = *(const short8*)&lb_[(bRd + nf*1024) ^ 32]; \
    STAGE_STMT;                                                             \
    __builtin_amdgcn_s_setprio(1);                                          \
    _Pragma("unroll")                                                       \
    for (int mf = 0; mf < 4; ++mf)                                          \
      _Pragma("unroll")                                                     \
      for (int nf = 0; nf < 4; ++nf)                                        \
        acc[mf][nf] = __builtin_amdgcn_mfma_f32_16x16x32_bf16(              \
            a0_[mf], b0_[nf], acc[mf][nf], 0, 0, 0);                        \
    _Pragma("unroll")                                                       \
    for (int mf = 0; mf < 4; ++mf)                                          \
      _Pragma("unroll")                                                     \
      for (int nf = 0; nf < 4; ++nf)                                        \
        acc[mf][nf] = __builtin_amdgcn_mfma_f32_16x16x32_bf16(              \
            a1_[mf], b1_[nf], acc[mf][nf], 0, 0, 0);                        \
    __builtin_amdgcn_s_setprio(0);                                          \
    VM_STMT;                                                                \
    if (DO_BAR) {                                                           \
      __builtin_amdgcn_s_barrier();                                         \
      __builtin_amdgcn_sched_barrier(0);                                    \
    }                                                                       \
  }

  unsigned short* b0 = &lds[0][0];
  unsigned short* b1 = &lds[1][0];
  unsigned short* b2 = &lds[2][0];

  // prologue: stage tiles 0,1 (12 loads/wave); wait stage(0) landed
  stage(0, b0);
  stage(1, b1);
  vm6();
  __builtin_amdgcn_s_barrier();
  __builtin_amdgcn_sched_barrier(0);

  // main loop: tiles 0..23 (slots cycle 0,1,2), 2-deep counted vmcnt(6)
  for (int t0 = 0; t0 < 24; t0 += 3) {
    PHASE(b0, { stage(t0 + 2, b2); }, vm6(), true);
    PHASE(b1, { stage(t0 + 3, b0); }, vm6(), true);
    PHASE(b2, { stage(t0 + 4, b1); }, vm6(), true);
  }
  // t=24: stage last tile (26 -> slot 2)
  PHASE(b0, { stage(26, b2); }, vm6(), true);
  // t=25: drain to 0 so tile 26's staging is visible
  PHASE(b1, {}, vm0(), true);
  // t=26: last tile, no wait/barrier needed
  PHASE(b2, {}, {}, false);
#undef PHASE

  // ---- epilogue: D col = lane&15 -> spatial, row = laneq*4+i -> Cout ----
  const int coB = cotile*BM + wm*64;
  const int fB  = stile*BN + wn*64;
  #pragma unroll
  for (int nf = 0; nf < 4; ++nf) {
    int f  = fB + nf*16 + lanep;
    int n  = f / SPAT;
    int sp = f % SPAT;
    float* obase = out + (size_t)n*C_OUT*SPAT + sp;
    #pragma unroll
    for (int mf = 0; mf < 4; ++mf) {
      #pragma unroll
      for (int i = 0; i < 4; ++i) {
        int co = coB + mf*16 + laneq*4 + i;
        obase[(size_t)co*SPAT] = acc[mf][nf][i] + bias[co];
      }
    }
  }
}

// ---- fallback: direct fp32 conv (used only if ws too small) ----
__global__ void conv_naive(const float* __restrict__ x, const float* __restrict__ W,
                           const float* __restrict__ bias, float* __restrict__ out) {
  size_t idx = (size_t)blockIdx.x*256 + threadIdx.x;
  if (idx >= (size_t)N_IMG*C_OUT*SPAT) return;
  int s  = idx % SPAT;
  int co = (int)((idx / SPAT) % C_OUT);
  int n  = (int)(idx / ((size_t)SPAT*C_OUT));
  int h = s / HW, w = s % HW;
  float acc = bias[co];
  for (int c = 0; c < C_IN; ++c)
    for (int kh = 0; kh < 3; ++kh) {
      int hh = h + kh - 1;
      if (hh < 0 || hh >= HW) continue;
      for (int kw = 0; kw < 3; ++kw) {
        int ww = w + kw - 1;
        if (ww < 0 || ww >= HW) continue;
        acc += x[(((size_t)n*C_IN + c)*HW + hh)*HW + ww]
             * W[(((size_t)co*C_IN + c)*3 + kh)*3 + kw];
      }
    }
  out[idx] = acc;
}

extern "C" void kernel_launch(void* const* d_in, const int* in_sizes, int n_in,
                              void* d_out, int out_size, void* d_ws, size_t ws_size,
                              hipStream_t stream) {
  const float* x = (const float*)d_in[0];
  const float* W = (const float*)d_in[1];
  const float* b = (const float*)d_in[2];
  float* out = (float*)d_out;

  const size_t WP_ELEMS = (size_t)C_OUT*KPOS*C_IN;        // 663,552
  const size_t XP_ELEMS = (size_t)N_IMG*HP*HP*C_IN;       // 20,668,416
  const size_t NEED = (WP_ELEMS + XP_ELEMS)*2;            // ~40.7 MB

  if (ws_size >= NEED) {
    unsigned short* Wp = (unsigned short*)d_ws;
    unsigned short* Xp = Wp + WP_ELEMS;                   // 16B-aligned
    zero_border<<<(N_IMG*228*C_IN + 255)/256, 256, 0, stream>>>(Xp);
    pack_w<<<(int)((WP_ELEMS + 255)/256), 256, 0, stream>>>(W, Wp);
    pack_x<<<N_IMG*HW*3, 256, 0, stream>>>(x, Xp);
    conv_gemm<<<GRID_MAIN, 512, 0, stream>>>(Wp, Xp, b, out);
  } else {
    size_t total = (size_t)N_IMG*C_OUT*SPAT;
    conv_naive<<<(int)((total + 255)/256), 256, 0, stream>>>(x, W, b, out);
  }
}